// Round 1
// baseline (530.831 us; speedup 1.0000x reference)
//
#include <hip/hip_runtime.h>
#include <hip/hip_bf16.h>

// ---------------- GEMM: C[N,M] = A[N,K] @ B[K,M], fp32, tiled ----------------
template<int BM, int BN, int BK>
__global__ __launch_bounds__(256) void gemm_kernel(const float* __restrict__ A,
                                                   const float* __restrict__ B,
                                                   float* __restrict__ C,
                                                   int N, int K, int M) {
  __shared__ float As[BK][BM + 4];
  __shared__ float Bs[BK][BN];
  const int tid = threadIdx.x;
  const int row0 = blockIdx.x * BM;
  const int col0 = blockIdx.y * BN;
  const int tx = tid % (BN / 4);   // 16
  const int ty = tid / (BN / 4);   // 16
  float acc[4][4] = {};

  for (int k0 = 0; k0 < K; k0 += BK) {
    // A tile: BM rows x BK k, 4 floats per thread
    {
      int r  = tid >> 2;
      int kq = (tid & 3) * 4;
      int row = row0 + r;
      float4 v = make_float4(0.f, 0.f, 0.f, 0.f);
      if (row < N) v = *(const float4*)(A + (size_t)row * K + k0 + kq);
      As[kq + 0][r] = v.x; As[kq + 1][r] = v.y;
      As[kq + 2][r] = v.z; As[kq + 3][r] = v.w;
    }
    // B tile: BK k x BN cols, 4 floats per thread
    {
      int kk = tid >> 4;
      int cq = (tid & 15) * 4;
      float4 v = *(const float4*)(B + (size_t)(k0 + kk) * M + col0 + cq);
      *(float4*)&Bs[kk][cq] = v;
    }
    __syncthreads();
#pragma unroll
    for (int kk = 0; kk < BK; ++kk) {
      float a[4], b[4];
#pragma unroll
      for (int i = 0; i < 4; ++i) a[i] = As[kk][ty * 4 + i];
#pragma unroll
      for (int j = 0; j < 4; ++j) b[j] = Bs[kk][tx * 4 + j];
#pragma unroll
      for (int i = 0; i < 4; ++i)
#pragma unroll
        for (int j = 0; j < 4; ++j)
          acc[i][j] += a[i] * b[j];
    }
    __syncthreads();
  }
#pragma unroll
  for (int i = 0; i < 4; ++i) {
    int row = row0 + ty * 4 + i;
    if (row < N) {
      float4 v = make_float4(acc[i][0], acc[i][1], acc[i][2], acc[i][3]);
      *(float4*)(C + (size_t)row * M + col0 + tx * 4) = v;
    }
  }
}

// ---------------- CSR build ----------------
__global__ void count_kernel(const int* __restrict__ ei, int E, int N,
                             int* __restrict__ counts) {
  int e = blockIdx.x * blockDim.x + threadIdx.x;
  int Et = E + N;
  if (e >= Et) return;
  int d = (e < E) ? ei[E + e] : (e - E);
  atomicAdd(&counts[d], 1);
}

__global__ void scan_kernel(const int* __restrict__ counts, int* __restrict__ offsets,
                            int* __restrict__ cursor, int N) {
  __shared__ int part[1024];
  int tid = threadIdx.x;
  int chunk = (N + 1023) / 1024;
  int start = tid * chunk;
  int end = min(start + chunk, N);
  if (start > N) start = N;
  int s = 0;
  for (int i = start; i < end; ++i) s += counts[i];
  part[tid] = s;
  __syncthreads();
  for (int off = 1; off < 1024; off <<= 1) {
    int o = (tid >= off) ? part[tid - off] : 0;
    __syncthreads();
    part[tid] += o;
    __syncthreads();
  }
  int run = part[tid] - s;  // exclusive prefix
  for (int i = start; i < end; ++i) {
    offsets[i] = run;
    cursor[i]  = run;
    run += counts[i];
  }
  if (end == N) offsets[N] = run;
}

__global__ void scatter_kernel(const int* __restrict__ ei, int E, int N,
                               int* __restrict__ cursor, int* __restrict__ csr_src) {
  int e = blockIdx.x * blockDim.x + threadIdx.x;
  int Et = E + N;
  if (e >= Et) return;
  int s, d;
  if (e < E) { s = ei[e]; d = ei[E + e]; }
  else       { s = d = e - E; }
  int pos = atomicAdd(&cursor[d], 1);
  csr_src[pos] = s;
}

// ---------------- attention scalars ----------------
// layer 1: H1 rows are 256 floats (2 heads x 128); att arrays flat [256]
__global__ void a1_kernel(const float* __restrict__ H1, const float* __restrict__ att_src,
                          const float* __restrict__ att_dst, float* __restrict__ a_src,
                          float* __restrict__ a_dst, int N) {
  int node = (blockIdx.x * blockDim.x + threadIdx.x) >> 6;
  int lane = threadIdx.x & 63;
  if (node >= N) return;
  float4 h  = *(const float4*)(H1 + (size_t)node * 256 + lane * 4);
  float4 as = *(const float4*)(att_src + lane * 4);
  float4 ad = *(const float4*)(att_dst + lane * 4);
  float ps = h.x * as.x + h.y * as.y + h.z * as.z + h.w * as.w;
  float pd = h.x * ad.x + h.y * ad.y + h.z * ad.z + h.w * ad.w;
  // reduce within each 32-lane half (head 0 = lanes 0..31, head 1 = lanes 32..63)
  for (int off = 16; off; off >>= 1) {
    ps += __shfl_xor(ps, off);
    pd += __shfl_xor(pd, off);
  }
  if (lane == 0)  { a_src[node * 2 + 0] = ps; a_dst[node * 2 + 0] = pd; }
  if (lane == 32) { a_src[node * 2 + 1] = ps; a_dst[node * 2 + 1] = pd; }
}

// layer 2: H2 rows are 64 floats, 1 head
__global__ void a2_kernel(const float* __restrict__ H2, const float* __restrict__ att_src,
                          const float* __restrict__ att_dst, float* __restrict__ a_src,
                          float* __restrict__ a_dst, int N) {
  int node = (blockIdx.x * blockDim.x + threadIdx.x) >> 6;
  int lane = threadIdx.x & 63;
  if (node >= N) return;
  float h = H2[(size_t)node * 64 + lane];
  float ps = h * att_src[lane];
  float pd = h * att_dst[lane];
  for (int off = 32; off; off >>= 1) {
    ps += __shfl_xor(ps, off);
    pd += __shfl_xor(pd, off);
  }
  if (lane == 0) { a_src[node] = ps; a_dst[node] = pd; }
}

// ---------------- layer-1 aggregation: softmax + weighted sum + bias + ELU ----------------
__global__ void agg1_kernel(const float* __restrict__ H1, const int* __restrict__ offsets,
                            const int* __restrict__ csr_src,
                            const float* __restrict__ a_src, const float* __restrict__ a_dst,
                            const float* __restrict__ b1, float* __restrict__ out, int N) {
  int node = (blockIdx.x * blockDim.x + threadIdx.x) >> 6;
  int lane = threadIdx.x & 63;
  if (node >= N) return;
  int off = offsets[node];
  int deg = offsets[node + 1] - off;
  float ad0 = a_dst[node * 2 + 0];
  float ad1 = a_dst[node * 2 + 1];
  bool hi = lane >= 32;  // head 1 owns channels 128..255
  float4 acc = make_float4(0.f, 0.f, 0.f, 0.f);
  float den = 0.f;
  for (int base = 0; base < deg; base += 64) {
    int i = base + lane;
    int s = 0;
    float e0 = 0.f, e1 = 0.f;
    if (i < deg) {
      s = csr_src[off + i];
      float l0 = a_src[s * 2 + 0] + ad0;
      float l1 = a_src[s * 2 + 1] + ad1;
      l0 = l0 > 0.f ? l0 : 0.2f * l0;
      l1 = l1 > 0.f ? l1 : 0.2f * l1;
      e0 = __expf(l0);
      e1 = __expf(l1);
    }
    int cnt = min(64, deg - base);
    for (int j = 0; j < cnt; ++j) {
      int ss   = __shfl(s, j);
      float w0 = __shfl(e0, j);
      float w1 = __shfl(e1, j);
      float w  = hi ? w1 : w0;
      den += w;
      float4 hv = *(const float4*)(H1 + (size_t)ss * 256 + lane * 4);
      acc.x += w * hv.x; acc.y += w * hv.y;
      acc.z += w * hv.z; acc.w += w * hv.w;
    }
  }
  float inv = 1.f / (den + 1e-16f);
  float4 bb = *(const float4*)(b1 + lane * 4);
  float4 o;
  o.x = acc.x * inv + bb.x;
  o.y = acc.y * inv + bb.y;
  o.z = acc.z * inv + bb.z;
  o.w = acc.w * inv + bb.w;
  // ELU
  o.x = o.x > 0.f ? o.x : expm1f(o.x);
  o.y = o.y > 0.f ? o.y : expm1f(o.y);
  o.z = o.z > 0.f ? o.z : expm1f(o.z);
  o.w = o.w > 0.f ? o.w : expm1f(o.w);
  *(float4*)(out + (size_t)node * 256 + lane * 4) = o;
}

// ---------------- layer-2 aggregation + bias + log_softmax ----------------
__global__ void agg2_kernel(const float* __restrict__ H2, const int* __restrict__ offsets,
                            const int* __restrict__ csr_src,
                            const float* __restrict__ a_src, const float* __restrict__ a_dst,
                            const float* __restrict__ b2, float* __restrict__ out, int N) {
  int node = (blockIdx.x * blockDim.x + threadIdx.x) >> 6;
  int lane = threadIdx.x & 63;
  if (node >= N) return;
  int off = offsets[node];
  int deg = offsets[node + 1] - off;
  float ad = a_dst[node];
  float acc = 0.f, den = 0.f;
  for (int base = 0; base < deg; base += 64) {
    int i = base + lane;
    int s = 0;
    float e = 0.f;
    if (i < deg) {
      s = csr_src[off + i];
      float l = a_src[s] + ad;
      l = l > 0.f ? l : 0.2f * l;
      e = __expf(l);
    }
    int cnt = min(64, deg - base);
    for (int j = 0; j < cnt; ++j) {
      int ss  = __shfl(s, j);
      float w = __shfl(e, j);
      den += w;
      acc += w * H2[(size_t)ss * 64 + lane];
    }
  }
  float v = acc / (den + 1e-16f) + b2[lane];
  // log_softmax over the 64 lanes (= 64 classes)
  float m = v;
  for (int off2 = 32; off2; off2 >>= 1) m = fmaxf(m, __shfl_xor(m, off2));
  float ex = __expf(v - m);
  float sum = ex;
  for (int off2 = 32; off2; off2 >>= 1) sum += __shfl_xor(sum, off2);
  out[(size_t)node * 64 + lane] = v - m - logf(sum);
}

// ---------------- launch ----------------
extern "C" void kernel_launch(void* const* d_in, const int* in_sizes, int n_in,
                              void* d_out, int out_size, void* d_ws, size_t ws_size,
                              hipStream_t stream) {
  const float* x   = (const float*)d_in[0];
  const int*   ei  = (const int*)d_in[1];
  const float* W1  = (const float*)d_in[2];
  const float* as1 = (const float*)d_in[3];
  const float* ad1 = (const float*)d_in[4];
  const float* b1  = (const float*)d_in[5];
  const float* W2  = (const float*)d_in[6];
  const float* as2 = (const float*)d_in[7];
  const float* ad2 = (const float*)d_in[8];
  const float* b2  = (const float*)d_in[9];
  float* out = (float*)d_out;

  const int N  = in_sizes[0] / 256;
  const int E  = in_sizes[1] / 2;
  const int Et = E + N;

  char* p = (char*)d_ws;
  auto alloc = [&](size_t bytes) -> char* {
    char* r = p;
    p += (bytes + 255) & ~(size_t)255;
    return r;
  };
  float* H1     = (float*)alloc((size_t)N * 256 * 4);
  float* h1act  = (float*)alloc((size_t)N * 256 * 4);
  float* H2     = (float*)alloc((size_t)N * 64 * 4);
  float* a_src1 = (float*)alloc((size_t)N * 2 * 4);
  float* a_dst1 = (float*)alloc((size_t)N * 2 * 4);
  float* a_src2 = (float*)alloc((size_t)N * 4);
  float* a_dst2 = (float*)alloc((size_t)N * 4);
  int* counts   = (int*)alloc((size_t)N * 4);
  int* offsets  = (int*)alloc((size_t)(N + 1) * 4);
  int* cursor   = (int*)alloc((size_t)N * 4);
  int* csr_src  = (int*)alloc((size_t)Et * 4);

  const int tb = 256;

  // CSR build
  hipMemsetAsync(counts, 0, (size_t)N * 4, stream);
  count_kernel<<<(Et + tb - 1) / tb, tb, 0, stream>>>(ei, E, N, counts);
  scan_kernel<<<1, 1024, 0, stream>>>(counts, offsets, cursor, N);
  scatter_kernel<<<(Et + tb - 1) / tb, tb, 0, stream>>>(ei, E, N, cursor, csr_src);

  // layer 1
  dim3 g1((N + 63) / 64, 256 / 64);
  gemm_kernel<64, 64, 16><<<g1, 256, 0, stream>>>(x, W1, H1, N, 256, 256);
  a1_kernel<<<(N + 3) / 4, 256, 0, stream>>>(H1, as1, ad1, a_src1, a_dst1, N);
  agg1_kernel<<<(N + 3) / 4, 256, 0, stream>>>(H1, offsets, csr_src, a_src1, a_dst1, b1,
                                               h1act, N);

  // layer 2
  dim3 g2((N + 63) / 64, 1);
  gemm_kernel<64, 64, 16><<<g2, 256, 0, stream>>>(h1act, W2, H2, N, 256, 64);
  a2_kernel<<<(N + 3) / 4, 256, 0, stream>>>(H2, as2, ad2, a_src2, a_dst2, N);
  agg2_kernel<<<(N + 3) / 4, 256, 0, stream>>>(H2, offsets, csr_src, a_src2, a_dst2, b2,
                                               out, N);
}

// Round 2
// 386.935 us; speedup vs baseline: 1.3719x; 1.3719x over previous
//
#include <hip/hip_runtime.h>

typedef unsigned short u16;
typedef short bf8_t __attribute__((ext_vector_type(8)));
typedef float f32x4 __attribute__((ext_vector_type(4)));

__device__ inline u16 f2bf(float f) {
  unsigned u = __float_as_uint(f);
  u += 0x7FFFu + ((u >> 16) & 1u);
  return (u16)(u >> 16);
}
__device__ inline float bf2f(u16 h) { return __uint_as_float(((unsigned)h) << 16); }

// ---------------- W transpose + bf16 convert: W[K][M] -> WT[M][K] ----------------
__global__ void tp_kernel(const float* __restrict__ W, u16* __restrict__ WT, int K, int M) {
  int idx = blockIdx.x * 256 + threadIdx.x;
  if (idx >= K * M) return;
  int m = idx / K, k = idx % K;
  WT[idx] = f2bf(W[(size_t)k * M + m]);
}

// ---------------- MFMA GEMM: C[N][BN] = A[N][K] @ Bt[BN][K]^T, bf16 in LDS ----------------
// grid.x over rows; full output width BN per block. 4 waves, wave grid (BM/WM)x(BN/WN).
template<int BM, int BN, int BK, int WM, int WN, bool AF32>
__global__ __launch_bounds__(256) void mfma_gemm(const void* __restrict__ Ap,
                                                 const u16* __restrict__ Bt,
                                                 u16* __restrict__ C, int N, int K) {
  constexpr int PAD = 8;  // stride 40 shorts = 80 B: 16B-aligned rows, spread banks
  __shared__ u16 As[BM][BK + PAD];
  __shared__ u16 Bs[BN][BK + PAD];
  const int tid = threadIdx.x;
  const int row0 = blockIdx.x * BM;
  const int w = tid >> 6, lane = tid & 63;
  const int wr = (w / (BN / WN)) * WM;
  const int wc = (w % (BN / WN)) * WN;
  constexpr int MF = WM / 16, NF = WN / 16;
  constexpr int CPR = BK / 8;  // 16B chunks per row
  f32x4 acc[MF][NF] = {};

  for (int k0 = 0; k0 < K; k0 += BK) {
    // stage A (fp32->bf16 convert, or bf16 copy)
    constexpr int ACH = BM * CPR;
#pragma unroll
    for (int c = 0; c < ACH; c += 256) {
      int cc = c + tid;
      int r = cc / CPR, kc = cc % CPR;
      int row = row0 + r;
      if (AF32) {
        const float* A = (const float*)Ap;
        float4 v0 = make_float4(0.f, 0.f, 0.f, 0.f), v1 = v0;
        if (row < N) {
          const float* p = A + (size_t)row * K + k0 + kc * 8;
          v0 = *(const float4*)p;
          v1 = *(const float4*)(p + 4);
        }
        u16 tmp[8] = {f2bf(v0.x), f2bf(v0.y), f2bf(v0.z), f2bf(v0.w),
                      f2bf(v1.x), f2bf(v1.y), f2bf(v1.z), f2bf(v1.w)};
        *(uint4*)&As[r][kc * 8] = *(uint4*)tmp;
      } else {
        const u16* A = (const u16*)Ap;
        uint4 v = make_uint4(0, 0, 0, 0);
        if (row < N) v = *(const uint4*)(A + (size_t)row * K + k0 + kc * 8);
        *(uint4*)&As[r][kc * 8] = v;
      }
    }
    // stage B (already bf16, [BN][K] row-major)
    constexpr int BCH = BN * CPR;
#pragma unroll
    for (int c = 0; c < BCH; c += 256) {
      int cc = c + tid;
      int r = cc / CPR, kc = cc % CPR;
      *(uint4*)&Bs[r][kc * 8] = *(const uint4*)(Bt + (size_t)r * K + k0 + kc * 8);
    }
    __syncthreads();
    const int lr = lane & 15, lk = (lane >> 4) * 8;
    bf8_t a[MF], b[NF];
#pragma unroll
    for (int mi = 0; mi < MF; ++mi) a[mi] = *(bf8_t*)&As[wr + mi * 16 + lr][lk];
#pragma unroll
    for (int ni = 0; ni < NF; ++ni) b[ni] = *(bf8_t*)&Bs[wc + ni * 16 + lr][lk];
#pragma unroll
    for (int mi = 0; mi < MF; ++mi)
#pragma unroll
      for (int ni = 0; ni < NF; ++ni)
        acc[mi][ni] = __builtin_amdgcn_mfma_f32_16x16x32_bf16(a[mi], b[ni], acc[mi][ni], 0, 0, 0);
    __syncthreads();
  }
  // epilogue: C/D layout col=lane&15, row=(lane>>4)*4+reg  [m89-verified]
#pragma unroll
  for (int mi = 0; mi < MF; ++mi)
#pragma unroll
    for (int ni = 0; ni < NF; ++ni)
#pragma unroll
      for (int r = 0; r < 4; ++r) {
        int row = row0 + wr + mi * 16 + (lane >> 4) * 4 + r;
        int col = wc + ni * 16 + (lane & 15);
        if (row < N) C[(size_t)row * BN + col] = f2bf(acc[mi][ni][r]);
      }
}

// ---------------- CSR build ----------------
__global__ void count_kernel(const int* __restrict__ ei, int E, int N,
                             int* __restrict__ counts) {
  int e = blockIdx.x * blockDim.x + threadIdx.x;
  int Et = E + N;
  if (e >= Et) return;
  int d = (e < E) ? ei[E + e] : (e - E);
  atomicAdd(&counts[d], 1);
}

__global__ void scan_kernel(const int* __restrict__ counts, int* __restrict__ offsets,
                            int* __restrict__ cursor, int N) {
  __shared__ int part[1024];
  int tid = threadIdx.x;
  int chunk = (N + 1023) / 1024;
  int start = tid * chunk;
  int end = min(start + chunk, N);
  if (start > N) start = N;
  int s = 0;
  for (int i = start; i < end; ++i) s += counts[i];
  part[tid] = s;
  __syncthreads();
  for (int off = 1; off < 1024; off <<= 1) {
    int o = (tid >= off) ? part[tid - off] : 0;
    __syncthreads();
    part[tid] += o;
    __syncthreads();
  }
  int run = part[tid] - s;  // exclusive prefix
  for (int i = start; i < end; ++i) {
    offsets[i] = run;
    cursor[i]  = run;
    run += counts[i];
  }
  if (end == N) offsets[N] = run;
}

__global__ void scatter_kernel(const int* __restrict__ ei, int E, int N,
                               int* __restrict__ cursor, int* __restrict__ csr_src) {
  int e = blockIdx.x * blockDim.x + threadIdx.x;
  int Et = E + N;
  if (e >= Et) return;
  int s, d;
  if (e < E) { s = ei[e]; d = ei[E + e]; }
  else       { s = d = e - E; }
  int pos = atomicAdd(&cursor[d], 1);
  csr_src[pos] = s;
}

// ---------------- attention scalars ----------------
__global__ void a1_kernel(const u16* __restrict__ H1, const float* __restrict__ att_src,
                          const float* __restrict__ att_dst, float* __restrict__ a_src,
                          float* __restrict__ a_dst, int N) {
  int node = (blockIdx.x * blockDim.x + threadIdx.x) >> 6;
  int lane = threadIdx.x & 63;
  if (node >= N) return;
  ushort4 hv = *(const ushort4*)(H1 + (size_t)node * 256 + lane * 4);
  float h0 = bf2f(hv.x), h1 = bf2f(hv.y), h2 = bf2f(hv.z), h3 = bf2f(hv.w);
  float4 as = *(const float4*)(att_src + lane * 4);
  float4 ad = *(const float4*)(att_dst + lane * 4);
  float ps = h0 * as.x + h1 * as.y + h2 * as.z + h3 * as.w;
  float pd = h0 * ad.x + h1 * ad.y + h2 * ad.z + h3 * ad.w;
  for (int off = 16; off; off >>= 1) {
    ps += __shfl_xor(ps, off);
    pd += __shfl_xor(pd, off);
  }
  if (lane == 0)  { a_src[node * 2 + 0] = ps; a_dst[node * 2 + 0] = pd; }
  if (lane == 32) { a_src[node * 2 + 1] = ps; a_dst[node * 2 + 1] = pd; }
}

__global__ void a2_kernel(const u16* __restrict__ H2, const float* __restrict__ att_src,
                          const float* __restrict__ att_dst, float* __restrict__ a_src,
                          float* __restrict__ a_dst, int N) {
  int node = (blockIdx.x * blockDim.x + threadIdx.x) >> 6;
  int lane = threadIdx.x & 63;
  if (node >= N) return;
  float h = bf2f(H2[(size_t)node * 64 + lane]);
  float ps = h * att_src[lane];
  float pd = h * att_dst[lane];
  for (int off = 32; off; off >>= 1) {
    ps += __shfl_xor(ps, off);
    pd += __shfl_xor(pd, off);
  }
  if (lane == 0) { a_src[node] = ps; a_dst[node] = pd; }
}

// ---------------- layer-1 aggregation: softmax + weighted sum + bias + ELU ----------------
__global__ void agg1_kernel(const u16* __restrict__ H1, const int* __restrict__ offsets,
                            const int* __restrict__ csr_src,
                            const float* __restrict__ a_src, const float* __restrict__ a_dst,
                            const float* __restrict__ b1, u16* __restrict__ out, int N) {
  int node = (blockIdx.x * blockDim.x + threadIdx.x) >> 6;
  int lane = threadIdx.x & 63;
  if (node >= N) return;
  int off = offsets[node];
  int deg = offsets[node + 1] - off;
  float ad0 = a_dst[node * 2 + 0];
  float ad1 = a_dst[node * 2 + 1];
  bool hi = lane >= 32;  // head 1 owns channels 128..255
  float4 acc = make_float4(0.f, 0.f, 0.f, 0.f);
  float den = 0.f;
  for (int base = 0; base < deg; base += 64) {
    int i = base + lane;
    int s = 0;
    float e0 = 0.f, e1 = 0.f;
    if (i < deg) {
      s = csr_src[off + i];
      float l0 = a_src[s * 2 + 0] + ad0;
      float l1 = a_src[s * 2 + 1] + ad1;
      l0 = l0 > 0.f ? l0 : 0.2f * l0;
      l1 = l1 > 0.f ? l1 : 0.2f * l1;
      e0 = __expf(l0);
      e1 = __expf(l1);
    }
    int cnt = min(64, deg - base);
    for (int j = 0; j < cnt; ++j) {
      int ss   = __shfl(s, j);
      float w0 = __shfl(e0, j);
      float w1 = __shfl(e1, j);
      float w  = hi ? w1 : w0;
      den += w;
      uint2 u = *(const uint2*)(H1 + (size_t)ss * 256 + lane * 4);
      acc.x += w * __uint_as_float(u.x << 16);
      acc.y += w * __uint_as_float(u.x & 0xffff0000u);
      acc.z += w * __uint_as_float(u.y << 16);
      acc.w += w * __uint_as_float(u.y & 0xffff0000u);
    }
  }
  float inv = 1.f / (den + 1e-16f);
  float4 bb = *(const float4*)(b1 + lane * 4);
  float o0 = acc.x * inv + bb.x;
  float o1 = acc.y * inv + bb.y;
  float o2 = acc.z * inv + bb.z;
  float o3 = acc.w * inv + bb.w;
  o0 = o0 > 0.f ? o0 : expm1f(o0);
  o1 = o1 > 0.f ? o1 : expm1f(o1);
  o2 = o2 > 0.f ? o2 : expm1f(o2);
  o3 = o3 > 0.f ? o3 : expm1f(o3);
  uint2 ov;
  ov.x = (unsigned)f2bf(o0) | ((unsigned)f2bf(o1) << 16);
  ov.y = (unsigned)f2bf(o2) | ((unsigned)f2bf(o3) << 16);
  *(uint2*)(out + (size_t)node * 256 + lane * 4) = ov;
}

// ---------------- layer-2 aggregation + bias + log_softmax ----------------
__global__ void agg2_kernel(const u16* __restrict__ H2, const int* __restrict__ offsets,
                            const int* __restrict__ csr_src,
                            const float* __restrict__ a_src, const float* __restrict__ a_dst,
                            const float* __restrict__ b2, float* __restrict__ out, int N) {
  int node = (blockIdx.x * blockDim.x + threadIdx.x) >> 6;
  int lane = threadIdx.x & 63;
  if (node >= N) return;
  int off = offsets[node];
  int deg = offsets[node + 1] - off;
  float ad = a_dst[node];
  float acc = 0.f, den = 0.f;
  for (int base = 0; base < deg; base += 64) {
    int i = base + lane;
    int s = 0;
    float e = 0.f;
    if (i < deg) {
      s = csr_src[off + i];
      float l = a_src[s] + ad;
      l = l > 0.f ? l : 0.2f * l;
      e = __expf(l);
    }
    int cnt = min(64, deg - base);
    for (int j = 0; j < cnt; ++j) {
      int ss  = __shfl(s, j);
      float w = __shfl(e, j);
      den += w;
      acc += w * bf2f(H2[(size_t)ss * 64 + lane]);
    }
  }
  float v = acc / (den + 1e-16f) + b2[lane];
  float m = v;
  for (int off2 = 32; off2; off2 >>= 1) m = fmaxf(m, __shfl_xor(m, off2));
  float ex = __expf(v - m);
  float sum = ex;
  for (int off2 = 32; off2; off2 >>= 1) sum += __shfl_xor(sum, off2);
  out[(size_t)node * 64 + lane] = v - m - logf(sum);
}

// ---------------- launch ----------------
extern "C" void kernel_launch(void* const* d_in, const int* in_sizes, int n_in,
                              void* d_out, int out_size, void* d_ws, size_t ws_size,
                              hipStream_t stream) {
  const float* x   = (const float*)d_in[0];
  const int*   ei  = (const int*)d_in[1];
  const float* W1  = (const float*)d_in[2];
  const float* as1 = (const float*)d_in[3];
  const float* ad1 = (const float*)d_in[4];
  const float* b1  = (const float*)d_in[5];
  const float* W2  = (const float*)d_in[6];
  const float* as2 = (const float*)d_in[7];
  const float* ad2 = (const float*)d_in[8];
  const float* b2  = (const float*)d_in[9];
  float* out = (float*)d_out;

  const int N  = in_sizes[0] / 256;
  const int E  = in_sizes[1] / 2;
  const int Et = E + N;

  char* p = (char*)d_ws;
  auto alloc = [&](size_t bytes) -> char* {
    char* r = p;
    p += (bytes + 255) & ~(size_t)255;
    return r;
  };
  u16* H1b     = (u16*)alloc((size_t)N * 256 * 2);
  u16* h1act   = (u16*)alloc((size_t)N * 256 * 2);
  u16* H2b     = (u16*)alloc((size_t)N * 64 * 2);
  u16* W1T     = (u16*)alloc((size_t)256 * 256 * 2);
  u16* W2T     = (u16*)alloc((size_t)64 * 256 * 2);
  float* a_src1 = (float*)alloc((size_t)N * 2 * 4);
  float* a_dst1 = (float*)alloc((size_t)N * 2 * 4);
  float* a_src2 = (float*)alloc((size_t)N * 4);
  float* a_dst2 = (float*)alloc((size_t)N * 4);
  int* counts   = (int*)alloc((size_t)N * 4);
  int* offsets  = (int*)alloc((size_t)(N + 1) * 4);
  int* cursor   = (int*)alloc((size_t)N * 4);
  int* csr_src  = (int*)alloc((size_t)Et * 4);

  const int tb = 256;

  // CSR build
  hipMemsetAsync(counts, 0, (size_t)N * 4, stream);
  count_kernel<<<(Et + tb - 1) / tb, tb, 0, stream>>>(ei, E, N, counts);
  scan_kernel<<<1, 1024, 0, stream>>>(counts, offsets, cursor, N);
  scatter_kernel<<<(Et + tb - 1) / tb, tb, 0, stream>>>(ei, E, N, cursor, csr_src);

  // weight transposes (bf16)
  tp_kernel<<<(256 * 256 + tb - 1) / tb, tb, 0, stream>>>(W1, W1T, 256, 256);
  tp_kernel<<<(64 * 256 + tb - 1) / tb, tb, 0, stream>>>(W2, W2T, 256, 64);

  // layer 1: H1 = x @ W1  (bf16 MFMA), then attention + aggregate
  mfma_gemm<64, 256, 32, 64, 64, true><<<(N + 63) / 64, 256, 0, stream>>>(x, W1T, H1b, N, 256);
  a1_kernel<<<(N + 3) / 4, 256, 0, stream>>>(H1b, as1, ad1, a_src1, a_dst1, N);
  agg1_kernel<<<(N + 3) / 4, 256, 0, stream>>>(H1b, offsets, csr_src, a_src1, a_dst1, b1,
                                               h1act, N);

  // layer 2
  mfma_gemm<128, 64, 32, 32, 64, false><<<(N + 127) / 128, 256, 0, stream>>>(h1act, W2T, H2b, N, 256);
  a2_kernel<<<(N + 3) / 4, 256, 0, stream>>>(H2b, as2, ad2, a_src2, a_dst2, N);
  agg2_kernel<<<(N + 3) / 4, 256, 0, stream>>>(H2b, offsets, csr_src, a_src2, a_dst2, b2,
                                               out, N);
}

// Round 3
// 289.698 us; speedup vs baseline: 1.8324x; 1.3356x over previous
//
#include <hip/hip_runtime.h>

typedef unsigned short u16;
typedef short bf8_t __attribute__((ext_vector_type(8)));
typedef float f32x4 __attribute__((ext_vector_type(4)));

__device__ inline u16 f2bf(float f) {
  unsigned u = __float_as_uint(f);
  u += 0x7FFFu + ((u >> 16) & 1u);
  return (u16)(u >> 16);
}
__device__ inline float bf2f(u16 h) { return __uint_as_float(((unsigned)h) << 16); }

// ---------------- W transpose + bf16 convert: W[K][M] -> WT[M][K] ----------------
__global__ void tp_kernel(const float* __restrict__ W, u16* __restrict__ WT, int K, int M) {
  int idx = blockIdx.x * 256 + threadIdx.x;
  if (idx >= K * M) return;
  int m = idx / K, k = idx % K;
  WT[idx] = f2bf(W[(size_t)k * M + m]);
}

// ---------------- MFMA GEMM: C[N][BN] = A[N][K] @ Bt[BN][K]^T, bf16 in LDS ----------------
template<int BM, int BN, int BK, int WM, int WN, bool AF32>
__global__ __launch_bounds__(256) void mfma_gemm(const void* __restrict__ Ap,
                                                 const u16* __restrict__ Bt,
                                                 u16* __restrict__ C, int N, int K) {
  constexpr int PAD = 8;  // stride 40 shorts = 80 B: 16B-aligned rows, spread banks
  __shared__ u16 As[BM][BK + PAD];
  __shared__ u16 Bs[BN][BK + PAD];
  const int tid = threadIdx.x;
  const int row0 = blockIdx.x * BM;
  const int w = tid >> 6, lane = tid & 63;
  const int wr = (w / (BN / WN)) * WM;
  const int wc = (w % (BN / WN)) * WN;
  constexpr int MF = WM / 16, NF = WN / 16;
  constexpr int CPR = BK / 8;  // 16B chunks per row
  f32x4 acc[MF][NF] = {};

  for (int k0 = 0; k0 < K; k0 += BK) {
    constexpr int ACH = BM * CPR;
#pragma unroll
    for (int c = 0; c < ACH; c += 256) {
      int cc = c + tid;
      int r = cc / CPR, kc = cc % CPR;
      int row = row0 + r;
      if (AF32) {
        const float* A = (const float*)Ap;
        float4 v0 = make_float4(0.f, 0.f, 0.f, 0.f), v1 = v0;
        if (row < N) {
          const float* p = A + (size_t)row * K + k0 + kc * 8;
          v0 = *(const float4*)p;
          v1 = *(const float4*)(p + 4);
        }
        u16 tmp[8] = {f2bf(v0.x), f2bf(v0.y), f2bf(v0.z), f2bf(v0.w),
                      f2bf(v1.x), f2bf(v1.y), f2bf(v1.z), f2bf(v1.w)};
        *(uint4*)&As[r][kc * 8] = *(uint4*)tmp;
      } else {
        const u16* A = (const u16*)Ap;
        uint4 v = make_uint4(0, 0, 0, 0);
        if (row < N) v = *(const uint4*)(A + (size_t)row * K + k0 + kc * 8);
        *(uint4*)&As[r][kc * 8] = v;
      }
    }
    constexpr int BCH = BN * CPR;
#pragma unroll
    for (int c = 0; c < BCH; c += 256) {
      int cc = c + tid;
      int r = cc / CPR, kc = cc % CPR;
      *(uint4*)&Bs[r][kc * 8] = *(const uint4*)(Bt + (size_t)r * K + k0 + kc * 8);
    }
    __syncthreads();
    const int lr = lane & 15, lk = (lane >> 4) * 8;
    bf8_t a[MF], b[NF];
#pragma unroll
    for (int mi = 0; mi < MF; ++mi) a[mi] = *(bf8_t*)&As[wr + mi * 16 + lr][lk];
#pragma unroll
    for (int ni = 0; ni < NF; ++ni) b[ni] = *(bf8_t*)&Bs[wc + ni * 16 + lr][lk];
#pragma unroll
    for (int mi = 0; mi < MF; ++mi)
#pragma unroll
      for (int ni = 0; ni < NF; ++ni)
        acc[mi][ni] = __builtin_amdgcn_mfma_f32_16x16x32_bf16(a[mi], b[ni], acc[mi][ni], 0, 0, 0);
    __syncthreads();
  }
#pragma unroll
  for (int mi = 0; mi < MF; ++mi)
#pragma unroll
    for (int ni = 0; ni < NF; ++ni)
#pragma unroll
      for (int r = 0; r < 4; ++r) {
        int row = row0 + wr + mi * 16 + (lane >> 4) * 4 + r;
        int col = wc + ni * 16 + (lane & 15);
        if (row < N) C[(size_t)row * BN + col] = f2bf(acc[mi][ni][r]);
      }
}

// ---------------- CSR build ----------------
__global__ void count_kernel(const int* __restrict__ ei, int E, int N,
                             int* __restrict__ counts) {
  int e = blockIdx.x * blockDim.x + threadIdx.x;
  int Et = E + N;
  if (e >= Et) return;
  int d = (e < E) ? ei[E + e] : (e - E);
  atomicAdd(&counts[d], 1);
}

// phase 1: per-block exclusive scan of counts -> offsets, block totals -> bsums
__global__ void block_scan_kernel(const int* __restrict__ counts, int* __restrict__ offsets,
                                  int* __restrict__ bsums, int N) {
  __shared__ int sm[256];
  int tid = threadIdx.x;
  int gid = blockIdx.x * 256 + tid;
  int v = (gid < N) ? counts[gid] : 0;
  int val = v;
  sm[tid] = val;
  __syncthreads();
  for (int off = 1; off < 256; off <<= 1) {
    int o = (tid >= off) ? sm[tid - off] : 0;
    __syncthreads();
    val += o;
    sm[tid] = val;
    __syncthreads();
  }
  if (gid < N) offsets[gid] = val - v;  // exclusive within block
  if (tid == 255) bsums[blockIdx.x] = val;
}

// phase 2: single-block scan of block sums (nb <= 1024); writes exclusive bases in-place
__global__ void scan_sums_kernel(int* __restrict__ bsums, int* __restrict__ offsets,
                                 int nb, int N) {
  __shared__ int sm[1024];
  int tid = threadIdx.x;
  int v = (tid < nb) ? bsums[tid] : 0;
  int val = v;
  sm[tid] = val;
  __syncthreads();
  for (int off = 1; off < 1024; off <<= 1) {
    int o = (tid >= off) ? sm[tid - off] : 0;
    __syncthreads();
    val += o;
    sm[tid] = val;
    __syncthreads();
  }
  if (tid < nb) bsums[tid] = val - v;  // exclusive base
  if (tid == 1023) offsets[N] = val;   // grand total
}

// phase 3: add base, init cursor
__global__ void add_base_kernel(int* __restrict__ offsets, int* __restrict__ cursor,
                                const int* __restrict__ bsums, int N) {
  int gid = blockIdx.x * 256 + threadIdx.x;
  if (gid >= N) return;
  int o = offsets[gid] + bsums[blockIdx.x];
  offsets[gid] = o;
  cursor[gid] = o;
}

__global__ void scatter_kernel(const int* __restrict__ ei, int E, int N,
                               int* __restrict__ cursor, int* __restrict__ csr_src) {
  int e = blockIdx.x * blockDim.x + threadIdx.x;
  int Et = E + N;
  if (e >= Et) return;
  int s, d;
  if (e < E) { s = ei[e]; d = ei[E + e]; }
  else       { s = d = e - E; }
  int pos = atomicAdd(&cursor[d], 1);
  csr_src[pos] = s;
}

// ---------------- attention scalars ----------------
__global__ void a1_kernel(const u16* __restrict__ H1, const float* __restrict__ att_src,
                          const float* __restrict__ att_dst, float* __restrict__ a_src,
                          float* __restrict__ a_dst, int N) {
  int node = (blockIdx.x * blockDim.x + threadIdx.x) >> 6;
  int lane = threadIdx.x & 63;
  if (node >= N) return;
  ushort4 hv = *(const ushort4*)(H1 + (size_t)node * 256 + lane * 4);
  float h0 = bf2f(hv.x), h1 = bf2f(hv.y), h2 = bf2f(hv.z), h3 = bf2f(hv.w);
  float4 as = *(const float4*)(att_src + lane * 4);
  float4 ad = *(const float4*)(att_dst + lane * 4);
  float ps = h0 * as.x + h1 * as.y + h2 * as.z + h3 * as.w;
  float pd = h0 * ad.x + h1 * ad.y + h2 * ad.z + h3 * ad.w;
  for (int off = 16; off; off >>= 1) {
    ps += __shfl_xor(ps, off);
    pd += __shfl_xor(pd, off);
  }
  if (lane == 0)  { a_src[node * 2 + 0] = ps; a_dst[node * 2 + 0] = pd; }
  if (lane == 32) { a_src[node * 2 + 1] = ps; a_dst[node * 2 + 1] = pd; }
}

__global__ void a2_kernel(const u16* __restrict__ H2, const float* __restrict__ att_src,
                          const float* __restrict__ att_dst, float* __restrict__ a_src,
                          float* __restrict__ a_dst, int N) {
  int node = (blockIdx.x * blockDim.x + threadIdx.x) >> 6;
  int lane = threadIdx.x & 63;
  if (node >= N) return;
  float h = bf2f(H2[(size_t)node * 64 + lane]);
  float ps = h * att_src[lane];
  float pd = h * att_dst[lane];
  for (int off = 32; off; off >>= 1) {
    ps += __shfl_xor(ps, off);
    pd += __shfl_xor(pd, off);
  }
  if (lane == 0) { a_src[node] = ps; a_dst[node] = pd; }
}

// ---------------- layer-1 aggregation: softmax + weighted sum + bias + ELU ----------------
__global__ void agg1_kernel(const u16* __restrict__ H1, const int* __restrict__ offsets,
                            const int* __restrict__ csr_src,
                            const float* __restrict__ a_src, const float* __restrict__ a_dst,
                            const float* __restrict__ b1, u16* __restrict__ out, int N) {
  int node = (blockIdx.x * blockDim.x + threadIdx.x) >> 6;
  int lane = threadIdx.x & 63;
  if (node >= N) return;
  int off = offsets[node];
  int deg = offsets[node + 1] - off;
  float ad0 = a_dst[node * 2 + 0];
  float ad1 = a_dst[node * 2 + 1];
  bool hi = lane >= 32;  // head 1 owns channels 128..255
  float4 acc = make_float4(0.f, 0.f, 0.f, 0.f);
  float den = 0.f;
  for (int base = 0; base < deg; base += 64) {
    int i = base + lane;
    int s = 0;
    float e0 = 0.f, e1 = 0.f;
    if (i < deg) {
      s = csr_src[off + i];
      float l0 = a_src[s * 2 + 0] + ad0;
      float l1 = a_src[s * 2 + 1] + ad1;
      l0 = l0 > 0.f ? l0 : 0.2f * l0;
      l1 = l1 > 0.f ? l1 : 0.2f * l1;
      e0 = __expf(l0);
      e1 = __expf(l1);
    }
    int cnt = min(64, deg - base);
    for (int j = 0; j < cnt; ++j) {
      int ss   = __shfl(s, j);
      float w0 = __shfl(e0, j);
      float w1 = __shfl(e1, j);
      float w  = hi ? w1 : w0;
      den += w;
      uint2 u = *(const uint2*)(H1 + (size_t)ss * 256 + lane * 4);
      acc.x += w * __uint_as_float(u.x << 16);
      acc.y += w * __uint_as_float(u.x & 0xffff0000u);
      acc.z += w * __uint_as_float(u.y << 16);
      acc.w += w * __uint_as_float(u.y & 0xffff0000u);
    }
  }
  float inv = 1.f / (den + 1e-16f);
  float4 bb = *(const float4*)(b1 + lane * 4);
  float o0 = acc.x * inv + bb.x;
  float o1 = acc.y * inv + bb.y;
  float o2 = acc.z * inv + bb.z;
  float o3 = acc.w * inv + bb.w;
  o0 = o0 > 0.f ? o0 : expm1f(o0);
  o1 = o1 > 0.f ? o1 : expm1f(o1);
  o2 = o2 > 0.f ? o2 : expm1f(o2);
  o3 = o3 > 0.f ? o3 : expm1f(o3);
  uint2 ov;
  ov.x = (unsigned)f2bf(o0) | ((unsigned)f2bf(o1) << 16);
  ov.y = (unsigned)f2bf(o2) | ((unsigned)f2bf(o3) << 16);
  *(uint2*)(out + (size_t)node * 256 + lane * 4) = ov;
}

// ---------------- layer-2 aggregation + bias + log_softmax ----------------
__global__ void agg2_kernel(const u16* __restrict__ H2, const int* __restrict__ offsets,
                            const int* __restrict__ csr_src,
                            const float* __restrict__ a_src, const float* __restrict__ a_dst,
                            const float* __restrict__ b2, float* __restrict__ out, int N) {
  int node = (blockIdx.x * blockDim.x + threadIdx.x) >> 6;
  int lane = threadIdx.x & 63;
  if (node >= N) return;
  int off = offsets[node];
  int deg = offsets[node + 1] - off;
  float ad = a_dst[node];
  float acc = 0.f, den = 0.f;
  for (int base = 0; base < deg; base += 64) {
    int i = base + lane;
    int s = 0;
    float e = 0.f;
    if (i < deg) {
      s = csr_src[off + i];
      float l = a_src[s] + ad;
      l = l > 0.f ? l : 0.2f * l;
      e = __expf(l);
    }
    int cnt = min(64, deg - base);
    for (int j = 0; j < cnt; ++j) {
      int ss  = __shfl(s, j);
      float w = __shfl(e, j);
      den += w;
      acc += w * bf2f(H2[(size_t)ss * 64 + lane]);
    }
  }
  float v = acc / (den + 1e-16f) + b2[lane];
  float m = v;
  for (int off2 = 32; off2; off2 >>= 1) m = fmaxf(m, __shfl_xor(m, off2));
  float ex = __expf(v - m);
  float sum = ex;
  for (int off2 = 32; off2; off2 >>= 1) sum += __shfl_xor(sum, off2);
  out[(size_t)node * 64 + lane] = v - m - logf(sum);
}

// ---------------- launch ----------------
extern "C" void kernel_launch(void* const* d_in, const int* in_sizes, int n_in,
                              void* d_out, int out_size, void* d_ws, size_t ws_size,
                              hipStream_t stream) {
  const float* x   = (const float*)d_in[0];
  const int*   ei  = (const int*)d_in[1];
  const float* W1  = (const float*)d_in[2];
  const float* as1 = (const float*)d_in[3];
  const float* ad1 = (const float*)d_in[4];
  const float* b1  = (const float*)d_in[5];
  const float* W2  = (const float*)d_in[6];
  const float* as2 = (const float*)d_in[7];
  const float* ad2 = (const float*)d_in[8];
  const float* b2  = (const float*)d_in[9];
  float* out = (float*)d_out;

  const int N  = in_sizes[0] / 256;
  const int E  = in_sizes[1] / 2;
  const int Et = E + N;
  const int nb = (N + 255) / 256;  // scan blocks (196 for N=50000, must be <= 1024)

  char* p = (char*)d_ws;
  auto alloc = [&](size_t bytes) -> char* {
    char* r = p;
    p += (bytes + 255) & ~(size_t)255;
    return r;
  };
  u16* H1b     = (u16*)alloc((size_t)N * 256 * 2);
  u16* h1act   = (u16*)alloc((size_t)N * 256 * 2);
  u16* H2b     = (u16*)alloc((size_t)N * 64 * 2);
  u16* W1T     = (u16*)alloc((size_t)256 * 256 * 2);
  u16* W2T     = (u16*)alloc((size_t)64 * 256 * 2);
  float* a_src1 = (float*)alloc((size_t)N * 2 * 4);
  float* a_dst1 = (float*)alloc((size_t)N * 2 * 4);
  float* a_src2 = (float*)alloc((size_t)N * 4);
  float* a_dst2 = (float*)alloc((size_t)N * 4);
  int* counts   = (int*)alloc((size_t)N * 4);
  int* offsets  = (int*)alloc((size_t)(N + 1) * 4);
  int* cursor   = (int*)alloc((size_t)N * 4);
  int* bsums    = (int*)alloc((size_t)1024 * 4);
  int* csr_src  = (int*)alloc((size_t)Et * 4);

  const int tb = 256;

  // CSR build (hierarchical scan)
  hipMemsetAsync(counts, 0, (size_t)N * 4, stream);
  count_kernel<<<(Et + tb - 1) / tb, tb, 0, stream>>>(ei, E, N, counts);
  block_scan_kernel<<<nb, 256, 0, stream>>>(counts, offsets, bsums, N);
  scan_sums_kernel<<<1, 1024, 0, stream>>>(bsums, offsets, nb, N);
  add_base_kernel<<<nb, 256, 0, stream>>>(offsets, cursor, bsums, N);
  scatter_kernel<<<(Et + tb - 1) / tb, tb, 0, stream>>>(ei, E, N, cursor, csr_src);

  // weight transposes (bf16)
  tp_kernel<<<(256 * 256 + tb - 1) / tb, tb, 0, stream>>>(W1, W1T, 256, 256);
  tp_kernel<<<(64 * 256 + tb - 1) / tb, tb, 0, stream>>>(W2, W2T, 256, 64);

  // layer 1
  mfma_gemm<64, 256, 32, 64, 64, true><<<(N + 63) / 64, 256, 0, stream>>>(x, W1T, H1b, N, 256);
  a1_kernel<<<(N + 3) / 4, 256, 0, stream>>>(H1b, as1, ad1, a_src1, a_dst1, N);
  agg1_kernel<<<(N + 3) / 4, 256, 0, stream>>>(H1b, offsets, csr_src, a_src1, a_dst1, b1,
                                               h1act, N);

  // layer 2
  mfma_gemm<128, 64, 32, 32, 64, false><<<(N + 127) / 128, 256, 0, stream>>>(h1act, W2T, H2b, N, 256);
  a2_kernel<<<(N + 3) / 4, 256, 0, stream>>>(H2b, as2, ad2, a_src2, a_dst2, N);
  agg2_kernel<<<(N + 3) / 4, 256, 0, stream>>>(H2b, offsets, csr_src, a_src2, a_dst2, b2,
                                               out, N);
}

// Round 4
// 239.483 us; speedup vs baseline: 2.2166x; 1.2097x over previous
//
#include <hip/hip_runtime.h>

typedef unsigned short u16;
typedef short bf8_t __attribute__((ext_vector_type(8)));
typedef float f32x4 __attribute__((ext_vector_type(4)));

__device__ inline u16 f2bf(float f) {
  unsigned u = __float_as_uint(f);
  u += 0x7FFFu + ((u >> 16) & 1u);
  return (u16)(u >> 16);
}
__device__ inline float bf2f(u16 h) { return __uint_as_float(((unsigned)h) << 16); }
__device__ inline float bflo(unsigned u) { return __uint_as_float(u << 16); }
__device__ inline float bfhi(unsigned u) { return __uint_as_float(u & 0xffff0000u); }

// ---------------- W transpose + bf16 convert (both weights in one launch) ----------------
__global__ void tp_kernel(const float* __restrict__ W1, const float* __restrict__ W2,
                          u16* __restrict__ W1T, u16* __restrict__ W2T) {
  int idx = blockIdx.x * 256 + threadIdx.x;
  if (idx < 256 * 256) {
    int m = idx / 256, k = idx % 256;
    W1T[idx] = f2bf(W1[(size_t)k * 256 + m]);
  } else if (idx < 256 * 256 + 64 * 256) {
    int i = idx - 256 * 256;
    int m = i / 256, k = i % 256;
    W2T[i] = f2bf(W2[(size_t)k * 64 + m]);
  }
}

// ---------------- MFMA GEMM: C[N][BN] = A[N][K] @ Bt[BN][K]^T, bf16 ----------------
// EPI: 0=none, 1=layer1 attention epilogue (2 heads, cross-wave), 2=layer2 (1 head, in-wave)
template<int BM, int BN, int BK, int WM, int WN, bool AF32, int EPI>
__global__ __launch_bounds__(256) void mfma_gemm(const void* __restrict__ Ap,
                                                 const u16* __restrict__ Bt,
                                                 u16* __restrict__ C,
                                                 const float* __restrict__ att_s,
                                                 const float* __restrict__ att_d,
                                                 float* __restrict__ a_s,
                                                 float* __restrict__ a_d,
                                                 int N, int K) {
  constexpr int PAD = 8;
  __shared__ u16 As[BM][BK + PAD];
  __shared__ u16 Bs[BN][BK + PAD];
  const int tid = threadIdx.x;
  const int row0 = blockIdx.x * BM;
  const int w = tid >> 6, lane = tid & 63;
  const int wr = (w / (BN / WN)) * WM;
  const int wc = (w % (BN / WN)) * WN;
  constexpr int MF = WM / 16, NF = WN / 16;
  constexpr int CPR = BK / 8;
  f32x4 acc[MF][NF] = {};

  for (int k0 = 0; k0 < K; k0 += BK) {
    constexpr int ACH = BM * CPR;
#pragma unroll
    for (int c = 0; c < ACH; c += 256) {
      int cc = c + tid;
      int r = cc / CPR, kc = cc % CPR;
      int row = row0 + r;
      if (AF32) {
        const float* A = (const float*)Ap;
        float4 v0 = make_float4(0.f, 0.f, 0.f, 0.f), v1 = v0;
        if (row < N) {
          const float* p = A + (size_t)row * K + k0 + kc * 8;
          v0 = *(const float4*)p;
          v1 = *(const float4*)(p + 4);
        }
        u16 tmp[8] = {f2bf(v0.x), f2bf(v0.y), f2bf(v0.z), f2bf(v0.w),
                      f2bf(v1.x), f2bf(v1.y), f2bf(v1.z), f2bf(v1.w)};
        *(uint4*)&As[r][kc * 8] = *(uint4*)tmp;
      } else {
        const u16* A = (const u16*)Ap;
        uint4 v = make_uint4(0, 0, 0, 0);
        if (row < N) v = *(const uint4*)(A + (size_t)row * K + k0 + kc * 8);
        *(uint4*)&As[r][kc * 8] = v;
      }
    }
    constexpr int BCH = BN * CPR;
#pragma unroll
    for (int c = 0; c < BCH; c += 256) {
      int cc = c + tid;
      int r = cc / CPR, kc = cc % CPR;
      *(uint4*)&Bs[r][kc * 8] = *(const uint4*)(Bt + (size_t)r * K + k0 + kc * 8);
    }
    __syncthreads();
    const int lr = lane & 15, lk = (lane >> 4) * 8;
    bf8_t a[MF], b[NF];
#pragma unroll
    for (int mi = 0; mi < MF; ++mi) a[mi] = *(bf8_t*)&As[wr + mi * 16 + lr][lk];
#pragma unroll
    for (int ni = 0; ni < NF; ++ni) b[ni] = *(bf8_t*)&Bs[wc + ni * 16 + lr][lk];
#pragma unroll
    for (int mi = 0; mi < MF; ++mi)
#pragma unroll
      for (int ni = 0; ni < NF; ++ni)
        acc[mi][ni] = __builtin_amdgcn_mfma_f32_16x16x32_bf16(a[mi], b[ni], acc[mi][ni], 0, 0, 0);
    __syncthreads();
  }
  // C-write: col=lane&15, row=(lane>>4)*4+reg
#pragma unroll
  for (int mi = 0; mi < MF; ++mi)
#pragma unroll
    for (int ni = 0; ni < NF; ++ni)
#pragma unroll
      for (int r = 0; r < 4; ++r) {
        int row = row0 + wr + mi * 16 + (lane >> 4) * 4 + r;
        int col = wc + ni * 16 + (lane & 15);
        if (row < N) C[(size_t)row * BN + col] = f2bf(acc[mi][ni][r]);
      }

  // ---- fused attention-scalar epilogue ----
  if (EPI == 1) {
    // waves: wr=0 for all, wc=w*64; head = w>>1. Reduce per row across lane&15, then across col-waves.
    __shared__ float sm_s[4][64];
    __shared__ float sm_d[4][64];
    float asl[NF], adl[NF];
#pragma unroll
    for (int ni = 0; ni < NF; ++ni) {
      asl[ni] = att_s[wc + ni * 16 + (lane & 15)];
      adl[ni] = att_d[wc + ni * 16 + (lane & 15)];
    }
#pragma unroll
    for (int mi = 0; mi < MF; ++mi)
#pragma unroll
      for (int r = 0; r < 4; ++r) {
        float ps = 0.f, pd = 0.f;
#pragma unroll
        for (int ni = 0; ni < NF; ++ni) {
          float c = acc[mi][ni][r];
          ps += c * asl[ni];
          pd += c * adl[ni];
        }
#pragma unroll
        for (int o = 1; o < 16; o <<= 1) {
          ps += __shfl_xor(ps, o);
          pd += __shfl_xor(pd, o);
        }
        if ((lane & 15) == 0) {
          int row = mi * 16 + (lane >> 4) * 4 + r;
          sm_s[w][row] = ps;
          sm_d[w][row] = pd;
        }
      }
    __syncthreads();
    if (tid < 128) {
      int row = tid & 63, head = tid >> 6;
      int grow = row0 + row;
      if (grow < N) {
        a_s[grow * 2 + head] = sm_s[head * 2 + 0][row] + sm_s[head * 2 + 1][row];
        a_d[grow * 2 + head] = sm_d[head * 2 + 0][row] + sm_d[head * 2 + 1][row];
      }
    }
  } else if (EPI == 2) {
    // waves own disjoint rows (wr=w*32), full 64 cols in-wave; 1 head
    float asl[NF], adl[NF];
#pragma unroll
    for (int ni = 0; ni < NF; ++ni) {
      asl[ni] = att_s[ni * 16 + (lane & 15)];
      adl[ni] = att_d[ni * 16 + (lane & 15)];
    }
#pragma unroll
    for (int mi = 0; mi < MF; ++mi)
#pragma unroll
      for (int r = 0; r < 4; ++r) {
        float ps = 0.f, pd = 0.f;
#pragma unroll
        for (int ni = 0; ni < NF; ++ni) {
          float c = acc[mi][ni][r];
          ps += c * asl[ni];
          pd += c * adl[ni];
        }
#pragma unroll
        for (int o = 1; o < 16; o <<= 1) {
          ps += __shfl_xor(ps, o);
          pd += __shfl_xor(pd, o);
        }
        int row = row0 + wr + mi * 16 + (lane >> 4) * 4 + r;
        if ((lane & 15) == 0 && row < N) {
          a_s[row] = ps;
          a_d[row] = pd;
        }
      }
  }
}

// ---------------- CSR build ----------------
__global__ void count_kernel(const int* __restrict__ ei, int E, int N,
                             int* __restrict__ counts) {
  int e = blockIdx.x * blockDim.x + threadIdx.x;
  int Et = E + N;
  if (e >= Et) return;
  int d = (e < E) ? ei[E + e] : (e - E);
  atomicAdd(&counts[d], 1);
}

__global__ void block_scan_kernel(const int* __restrict__ counts, int* __restrict__ offsets,
                                  int* __restrict__ bsums, int N) {
  __shared__ int sm[256];
  int tid = threadIdx.x;
  int gid = blockIdx.x * 256 + tid;
  int v = (gid < N) ? counts[gid] : 0;
  int val = v;
  sm[tid] = val;
  __syncthreads();
  for (int off = 1; off < 256; off <<= 1) {
    int o = (tid >= off) ? sm[tid - off] : 0;
    __syncthreads();
    val += o;
    sm[tid] = val;
    __syncthreads();
  }
  if (gid < N) offsets[gid] = val - v;
  if (tid == 255) bsums[blockIdx.x] = val;
}

__global__ void scan_sums_kernel(int* __restrict__ bsums, int* __restrict__ offsets,
                                 int nb, int N) {
  __shared__ int sm[1024];
  int tid = threadIdx.x;
  int v = (tid < nb) ? bsums[tid] : 0;
  int val = v;
  sm[tid] = val;
  __syncthreads();
  for (int off = 1; off < 1024; off <<= 1) {
    int o = (tid >= off) ? sm[tid - off] : 0;
    __syncthreads();
    val += o;
    sm[tid] = val;
    __syncthreads();
  }
  if (tid < nb) bsums[tid] = val - v;
  if (tid == 1023) offsets[N] = val;
}

__global__ void add_base_kernel(int* __restrict__ offsets, int* __restrict__ cursor,
                                const int* __restrict__ bsums, int N) {
  int gid = blockIdx.x * 256 + threadIdx.x;
  if (gid >= N) return;
  int o = offsets[gid] + bsums[blockIdx.x];
  offsets[gid] = o;
  cursor[gid] = o;
}

__global__ void scatter_kernel(const int* __restrict__ ei, int E, int N,
                               int* __restrict__ cursor, int* __restrict__ csr_src) {
  int e = blockIdx.x * blockDim.x + threadIdx.x;
  int Et = E + N;
  if (e >= Et) return;
  int s, d;
  if (e < E) { s = ei[e]; d = ei[E + e]; }
  else       { s = d = e - E; }
  int pos = atomicAdd(&cursor[d], 1);
  csr_src[pos] = s;
}

// ---------------- layer-1 aggregation ----------------
__global__ void agg1_kernel(const u16* __restrict__ H1, const int* __restrict__ offsets,
                            const int* __restrict__ csr_src,
                            const float* __restrict__ a_src, const float* __restrict__ a_dst,
                            const float* __restrict__ b1, u16* __restrict__ out, int N) {
  __shared__ int4 meta[4][64];
  int wv = threadIdx.x >> 6;
  int lane = threadIdx.x & 63;
  int node = blockIdx.x * 4 + wv;
  if (node >= N) return;
  int off = offsets[node];
  int deg = offsets[node + 1] - off;
  float ad0 = a_dst[node * 2 + 0];
  float ad1 = a_dst[node * 2 + 1];
  bool hi = lane >= 32;
  const char* H1c = (const char*)H1;
  const unsigned loff = (unsigned)(lane * 8);
  float4 acc = make_float4(0.f, 0.f, 0.f, 0.f);
  float den = 0.f;
  const int4* mw = meta[wv];

  auto proc = [&](int4 m) {
    float w = hi ? __int_as_float(m.z) : __int_as_float(m.y);
    uint2 u = *(const uint2*)(H1c + (((unsigned)m.x << 9) + loff));
    den += w;
    acc.x += w * bflo(u.x);
    acc.y += w * bfhi(u.x);
    acc.z += w * bflo(u.y);
    acc.w += w * bfhi(u.y);
  };

  for (int base = 0; base < deg; base += 64) {
    int i = base + lane;
    if (i < deg) {
      int s = csr_src[off + i];
      float l0 = a_src[s * 2 + 0] + ad0;
      float l1 = a_src[s * 2 + 1] + ad1;
      l0 = l0 > 0.f ? l0 : 0.2f * l0;
      l1 = l1 > 0.f ? l1 : 0.2f * l1;
      meta[wv][lane] = make_int4(s, __float_as_int(__expf(l0)), __float_as_int(__expf(l1)), 0);
    }
    int cnt = min(64, deg - base);
    int j = 0;
    for (; j + 4 <= cnt; j += 4) {
      int4 m0 = mw[j], m1 = mw[j + 1], m2 = mw[j + 2], m3 = mw[j + 3];
      proc(m0); proc(m1); proc(m2); proc(m3);
    }
    for (; j < cnt; ++j) proc(mw[j]);
  }
  float inv = 1.f / (den + 1e-16f);
  float4 bb = *(const float4*)(b1 + lane * 4);
  float o0 = acc.x * inv + bb.x;
  float o1 = acc.y * inv + bb.y;
  float o2 = acc.z * inv + bb.z;
  float o3 = acc.w * inv + bb.w;
  o0 = o0 > 0.f ? o0 : expm1f(o0);
  o1 = o1 > 0.f ? o1 : expm1f(o1);
  o2 = o2 > 0.f ? o2 : expm1f(o2);
  o3 = o3 > 0.f ? o3 : expm1f(o3);
  uint2 ov;
  ov.x = (unsigned)f2bf(o0) | ((unsigned)f2bf(o1) << 16);
  ov.y = (unsigned)f2bf(o2) | ((unsigned)f2bf(o3) << 16);
  *(uint2*)(out + (size_t)node * 256 + lane * 4) = ov;
}

// ---------------- layer-2 aggregation + bias + log_softmax ----------------
__global__ void agg2_kernel(const u16* __restrict__ H2, const int* __restrict__ offsets,
                            const int* __restrict__ csr_src,
                            const float* __restrict__ a_src, const float* __restrict__ a_dst,
                            const float* __restrict__ b2, float* __restrict__ out, int N) {
  __shared__ int2 meta[4][64];
  int wv = threadIdx.x >> 6;
  int lane = threadIdx.x & 63;
  int node = blockIdx.x * 4 + wv;
  if (node >= N) return;
  int off = offsets[node];
  int deg = offsets[node + 1] - off;
  float ad = a_dst[node];
  const char* H2c = (const char*)H2;
  const unsigned loff = (unsigned)(lane * 2);
  float acc = 0.f, den = 0.f;
  const int2* mw = meta[wv];

  auto proc = [&](int2 m) {
    float w = __int_as_float(m.y);
    u16 hv = *(const u16*)(H2c + (((unsigned)m.x << 7) + loff));
    den += w;
    acc += w * bf2f(hv);
  };

  for (int base = 0; base < deg; base += 64) {
    int i = base + lane;
    if (i < deg) {
      int s = csr_src[off + i];
      float l = a_src[s] + ad;
      l = l > 0.f ? l : 0.2f * l;
      meta[wv][lane] = make_int2(s, __float_as_int(__expf(l)));
    }
    int cnt = min(64, deg - base);
    int j = 0;
    for (; j + 4 <= cnt; j += 4) {
      int2 m0 = mw[j], m1 = mw[j + 1], m2 = mw[j + 2], m3 = mw[j + 3];
      proc(m0); proc(m1); proc(m2); proc(m3);
    }
    for (; j < cnt; ++j) proc(mw[j]);
  }
  float v = acc / (den + 1e-16f) + b2[lane];
  float m = v;
  for (int o = 32; o; o >>= 1) m = fmaxf(m, __shfl_xor(m, o));
  float ex = __expf(v - m);
  float sum = ex;
  for (int o = 32; o; o >>= 1) sum += __shfl_xor(sum, o);
  out[(size_t)node * 64 + lane] = v - m - logf(sum);
}

// ---------------- launch ----------------
extern "C" void kernel_launch(void* const* d_in, const int* in_sizes, int n_in,
                              void* d_out, int out_size, void* d_ws, size_t ws_size,
                              hipStream_t stream) {
  const float* x   = (const float*)d_in[0];
  const int*   ei  = (const int*)d_in[1];
  const float* W1  = (const float*)d_in[2];
  const float* as1 = (const float*)d_in[3];
  const float* ad1 = (const float*)d_in[4];
  const float* b1  = (const float*)d_in[5];
  const float* W2  = (const float*)d_in[6];
  const float* as2 = (const float*)d_in[7];
  const float* ad2 = (const float*)d_in[8];
  const float* b2  = (const float*)d_in[9];
  float* out = (float*)d_out;

  const int N  = in_sizes[0] / 256;
  const int E  = in_sizes[1] / 2;
  const int Et = E + N;
  const int nb = (N + 255) / 256;

  char* p = (char*)d_ws;
  auto alloc = [&](size_t bytes) -> char* {
    char* r = p;
    p += (bytes + 255) & ~(size_t)255;
    return r;
  };
  u16* H1b     = (u16*)alloc((size_t)N * 256 * 2);
  u16* h1act   = (u16*)alloc((size_t)N * 256 * 2);
  u16* H2b     = (u16*)alloc((size_t)N * 64 * 2);
  u16* W1T     = (u16*)alloc((size_t)256 * 256 * 2);
  u16* W2T     = (u16*)alloc((size_t)64 * 256 * 2);
  float* a_src1 = (float*)alloc((size_t)N * 2 * 4);
  float* a_dst1 = (float*)alloc((size_t)N * 2 * 4);
  float* a_src2 = (float*)alloc((size_t)N * 4);
  float* a_dst2 = (float*)alloc((size_t)N * 4);
  int* counts   = (int*)alloc((size_t)N * 4);
  int* offsets  = (int*)alloc((size_t)(N + 1) * 4);
  int* cursor   = (int*)alloc((size_t)N * 4);
  int* bsums    = (int*)alloc((size_t)1024 * 4);
  int* csr_src  = (int*)alloc((size_t)Et * 4);

  const int tb = 256;

  // CSR build
  hipMemsetAsync(counts, 0, (size_t)N * 4, stream);
  count_kernel<<<(Et + tb - 1) / tb, tb, 0, stream>>>(ei, E, N, counts);
  block_scan_kernel<<<nb, 256, 0, stream>>>(counts, offsets, bsums, N);
  scan_sums_kernel<<<1, 1024, 0, stream>>>(bsums, offsets, nb, N);
  add_base_kernel<<<nb, 256, 0, stream>>>(offsets, cursor, bsums, N);
  scatter_kernel<<<(Et + tb - 1) / tb, tb, 0, stream>>>(ei, E, N, cursor, csr_src);

  // weight transposes (merged)
  tp_kernel<<<(256 * 256 + 64 * 256 + tb - 1) / tb, tb, 0, stream>>>(W1, W2, W1T, W2T);

  // layer 1: gemm + fused a1
  mfma_gemm<64, 256, 32, 64, 64, true, 1><<<(N + 63) / 64, 256, 0, stream>>>(
      x, W1T, H1b, as1, ad1, a_src1, a_dst1, N, 256);
  agg1_kernel<<<(N + 3) / 4, 256, 0, stream>>>(H1b, offsets, csr_src, a_src1, a_dst1, b1,
                                               h1act, N);

  // layer 2: gemm + fused a2
  mfma_gemm<128, 64, 32, 32, 64, false, 2><<<(N + 127) / 128, 256, 0, stream>>>(
      h1act, W2T, H2b, as2, ad2, a_src2, a_dst2, N, 256);
  agg2_kernel<<<(N + 3) / 4, 256, 0, stream>>>(H2b, offsets, csr_src, a_src2, a_dst2, b2,
                                               out, N);
}

// Round 5
// 233.136 us; speedup vs baseline: 2.2769x; 1.0272x over previous
//
#include <hip/hip_runtime.h>

typedef unsigned short u16;
typedef short bf8_t __attribute__((ext_vector_type(8)));
typedef float f32x4 __attribute__((ext_vector_type(4)));

__device__ inline u16 f2bf(float f) {
  unsigned u = __float_as_uint(f);
  u += 0x7FFFu + ((u >> 16) & 1u);
  return (u16)(u >> 16);
}
__device__ inline float bf2f(u16 h) { return __uint_as_float(((unsigned)h) << 16); }
__device__ inline float bflo(unsigned u) { return __uint_as_float(u << 16); }
__device__ inline float bfhi(unsigned u) { return __uint_as_float(u & 0xffff0000u); }

// ---------------- prep: edge-count histogram + both weight transposes ----------------
__global__ void prep_kernel(const int* __restrict__ ei, int E, int N,
                            int* __restrict__ counts,
                            const float* __restrict__ W1, const float* __restrict__ W2,
                            u16* __restrict__ W1T, u16* __restrict__ W2T, int nbc) {
  if ((int)blockIdx.x < nbc) {
    int e = blockIdx.x * 256 + threadIdx.x;
    int Et = E + N;
    if (e < Et) {
      int d = (e < E) ? ei[E + e] : (e - E);
      atomicAdd(&counts[d], 1);
    }
  } else {
    int idx = (blockIdx.x - nbc) * 256 + threadIdx.x;
    if (idx < 256 * 256) {
      int m = idx / 256, k = idx % 256;
      W1T[idx] = f2bf(W1[(size_t)k * 256 + m]);
    } else if (idx < 256 * 256 + 64 * 256) {
      int i = idx - 256 * 256;
      int m = i / 256, k = i % 256;
      W2T[i] = f2bf(W2[(size_t)k * 64 + m]);
    }
  }
}

// ---------------- MFMA GEMM: C[N][BN] = A[N][K] @ Bt[BN][K]^T, bf16 ----------------
// EPI: 1=layer1 attention epilogue (2 heads, cross-wave), 2=layer2 (1 head, in-wave)
template<int BM, int BN, int BK, int WM, int WN, bool AF32, int EPI>
__global__ __launch_bounds__(256) void mfma_gemm(const void* __restrict__ Ap,
                                                 const u16* __restrict__ Bt,
                                                 u16* __restrict__ C,
                                                 const float* __restrict__ att_s,
                                                 const float* __restrict__ att_d,
                                                 float* __restrict__ a_s,
                                                 float* __restrict__ a_d,
                                                 int N, int K) {
  constexpr int PAD = 8;
  __shared__ u16 As[BM][BK + PAD];
  __shared__ u16 Bs[BN][BK + PAD];
  const int tid = threadIdx.x;
  const int row0 = blockIdx.x * BM;
  const int w = tid >> 6, lane = tid & 63;
  const int wr = (w / (BN / WN)) * WM;
  const int wc = (w % (BN / WN)) * WN;
  constexpr int MF = WM / 16, NF = WN / 16;
  constexpr int CPR = BK / 8;
  f32x4 acc[MF][NF] = {};

  for (int k0 = 0; k0 < K; k0 += BK) {
    constexpr int ACH = BM * CPR;
#pragma unroll
    for (int c = 0; c < ACH; c += 256) {
      int cc = c + tid;
      int r = cc / CPR, kc = cc % CPR;
      int row = row0 + r;
      if (AF32) {
        const float* A = (const float*)Ap;
        float4 v0 = make_float4(0.f, 0.f, 0.f, 0.f), v1 = v0;
        if (row < N) {
          const float* p = A + (size_t)row * K + k0 + kc * 8;
          v0 = *(const float4*)p;
          v1 = *(const float4*)(p + 4);
        }
        u16 tmp[8] = {f2bf(v0.x), f2bf(v0.y), f2bf(v0.z), f2bf(v0.w),
                      f2bf(v1.x), f2bf(v1.y), f2bf(v1.z), f2bf(v1.w)};
        *(uint4*)&As[r][kc * 8] = *(uint4*)tmp;
      } else {
        const u16* A = (const u16*)Ap;
        uint4 v = make_uint4(0, 0, 0, 0);
        if (row < N) v = *(const uint4*)(A + (size_t)row * K + k0 + kc * 8);
        *(uint4*)&As[r][kc * 8] = v;
      }
    }
    constexpr int BCH = BN * CPR;
#pragma unroll
    for (int c = 0; c < BCH; c += 256) {
      int cc = c + tid;
      int r = cc / CPR, kc = cc % CPR;
      *(uint4*)&Bs[r][kc * 8] = *(const uint4*)(Bt + (size_t)r * K + k0 + kc * 8);
    }
    __syncthreads();
    const int lr = lane & 15, lk = (lane >> 4) * 8;
    bf8_t a[MF], b[NF];
#pragma unroll
    for (int mi = 0; mi < MF; ++mi) a[mi] = *(bf8_t*)&As[wr + mi * 16 + lr][lk];
#pragma unroll
    for (int ni = 0; ni < NF; ++ni) b[ni] = *(bf8_t*)&Bs[wc + ni * 16 + lr][lk];
#pragma unroll
    for (int mi = 0; mi < MF; ++mi)
#pragma unroll
      for (int ni = 0; ni < NF; ++ni)
        acc[mi][ni] = __builtin_amdgcn_mfma_f32_16x16x32_bf16(a[mi], b[ni], acc[mi][ni], 0, 0, 0);
    __syncthreads();
  }
  // C-write: col=lane&15, row=(lane>>4)*4+reg
#pragma unroll
  for (int mi = 0; mi < MF; ++mi)
#pragma unroll
    for (int ni = 0; ni < NF; ++ni)
#pragma unroll
      for (int r = 0; r < 4; ++r) {
        int row = row0 + wr + mi * 16 + (lane >> 4) * 4 + r;
        int col = wc + ni * 16 + (lane & 15);
        if (row < N) C[(size_t)row * BN + col] = f2bf(acc[mi][ni][r]);
      }

  // ---- fused attention-scalar epilogue ----
  if (EPI == 1) {
    __shared__ float sm_s[4][64];
    __shared__ float sm_d[4][64];
    float asl[NF], adl[NF];
#pragma unroll
    for (int ni = 0; ni < NF; ++ni) {
      asl[ni] = att_s[wc + ni * 16 + (lane & 15)];
      adl[ni] = att_d[wc + ni * 16 + (lane & 15)];
    }
#pragma unroll
    for (int mi = 0; mi < MF; ++mi)
#pragma unroll
      for (int r = 0; r < 4; ++r) {
        float ps = 0.f, pd = 0.f;
#pragma unroll
        for (int ni = 0; ni < NF; ++ni) {
          float c = acc[mi][ni][r];
          ps += c * asl[ni];
          pd += c * adl[ni];
        }
#pragma unroll
        for (int o = 1; o < 16; o <<= 1) {
          ps += __shfl_xor(ps, o);
          pd += __shfl_xor(pd, o);
        }
        if ((lane & 15) == 0) {
          int row = mi * 16 + (lane >> 4) * 4 + r;
          sm_s[w][row] = ps;
          sm_d[w][row] = pd;
        }
      }
    __syncthreads();
    if (tid < 128) {
      int row = tid & 63, head = tid >> 6;
      int grow = row0 + row;
      if (grow < N) {
        a_s[grow * 2 + head] = sm_s[head * 2 + 0][row] + sm_s[head * 2 + 1][row];
        a_d[grow * 2 + head] = sm_d[head * 2 + 0][row] + sm_d[head * 2 + 1][row];
      }
    }
  } else if (EPI == 2) {
    float asl[NF], adl[NF];
#pragma unroll
    for (int ni = 0; ni < NF; ++ni) {
      asl[ni] = att_s[ni * 16 + (lane & 15)];
      adl[ni] = att_d[ni * 16 + (lane & 15)];
    }
#pragma unroll
    for (int mi = 0; mi < MF; ++mi)
#pragma unroll
      for (int r = 0; r < 4; ++r) {
        float ps = 0.f, pd = 0.f;
#pragma unroll
        for (int ni = 0; ni < NF; ++ni) {
          float c = acc[mi][ni][r];
          ps += c * asl[ni];
          pd += c * adl[ni];
        }
#pragma unroll
        for (int o = 1; o < 16; o <<= 1) {
          ps += __shfl_xor(ps, o);
          pd += __shfl_xor(pd, o);
        }
        int row = row0 + wr + mi * 16 + (lane >> 4) * 4 + r;
        if ((lane & 15) == 0 && row < N) {
          a_s[row] = ps;
          a_d[row] = pd;
        }
      }
  }
}

// ---------------- CSR scan ----------------
__global__ void block_scan_kernel(const int* __restrict__ counts, int* __restrict__ offsets,
                                  int* __restrict__ bsums, int N) {
  __shared__ int sm[256];
  int tid = threadIdx.x;
  int gid = blockIdx.x * 256 + tid;
  int v = (gid < N) ? counts[gid] : 0;
  int val = v;
  sm[tid] = val;
  __syncthreads();
  for (int off = 1; off < 256; off <<= 1) {
    int o = (tid >= off) ? sm[tid - off] : 0;
    __syncthreads();
    val += o;
    sm[tid] = val;
    __syncthreads();
  }
  if (gid < N) offsets[gid] = val - v;
  if (tid == 255) bsums[blockIdx.x] = val;
}

__global__ void scan_sums_kernel(int* __restrict__ bsums, int* __restrict__ offsets,
                                 int nb, int N) {
  __shared__ int sm[1024];
  int tid = threadIdx.x;
  int v = (tid < nb) ? bsums[tid] : 0;
  int val = v;
  sm[tid] = val;
  __syncthreads();
  for (int off = 1; off < 1024; off <<= 1) {
    int o = (tid >= off) ? sm[tid - off] : 0;
    __syncthreads();
    val += o;
    sm[tid] = val;
    __syncthreads();
  }
  if (tid < nb) bsums[tid] = val - v;
  if (tid == 1023) offsets[N] = val;
}

__global__ void add_base_kernel(int* __restrict__ offsets, int* __restrict__ cursor,
                                const int* __restrict__ bsums, int N) {
  int gid = blockIdx.x * 256 + threadIdx.x;
  if (gid >= N) return;
  int o = offsets[gid] + bsums[blockIdx.x];
  offsets[gid] = o;
  cursor[gid] = o;
}

__global__ void scatter_kernel(const int* __restrict__ ei, int E, int N,
                               int* __restrict__ cursor, int* __restrict__ csr_src) {
  int e = blockIdx.x * blockDim.x + threadIdx.x;
  int Et = E + N;
  if (e >= Et) return;
  int s, d;
  if (e < E) { s = ei[e]; d = ei[E + e]; }
  else       { s = d = e - E; }
  int pos = atomicAdd(&cursor[d], 1);
  csr_src[pos] = s;
}

// ---------------- layer-1 aggregation: 2 edges/wave-step, 16B/lane ----------------
__global__ void agg1_kernel(const u16* __restrict__ H1, const int* __restrict__ offsets,
                            const int* __restrict__ csr_src,
                            const float* __restrict__ a_src, const float* __restrict__ a_dst,
                            const float* __restrict__ b1, u16* __restrict__ out, int N) {
  __shared__ int4 meta[4][64];
  int wv = threadIdx.x >> 6;
  int lane = threadIdx.x & 63;
  int node = blockIdx.x * 4 + wv;
  if (node >= N) return;
  int off = offsets[node];
  int deg = offsets[node + 1] - off;
  float ad0 = a_dst[node * 2 + 0];
  float ad1 = a_dst[node * 2 + 1];
  const int half = lane >> 5;     // which edge of a pair this lane serves
  const int l5 = lane & 31;       // owns channels l5*8 .. l5*8+7
  const bool head1 = (l5 >= 16);  // channels >=128 -> head 1
  const char* H1c = (const char*)H1;
  const unsigned loff = (unsigned)(l5 * 16);
  float acc[8] = {0.f, 0.f, 0.f, 0.f, 0.f, 0.f, 0.f, 0.f};
  float den = 0.f;
  const int4* mw = meta[wv];

  auto proc = [&](int jj) {
    int4 m = mw[jj];
    float w = head1 ? __int_as_float(m.z) : __int_as_float(m.y);
    uint4 u = *(const uint4*)(H1c + (((unsigned)m.x << 9) + loff));
    den += w;
    acc[0] += w * bflo(u.x); acc[1] += w * bfhi(u.x);
    acc[2] += w * bflo(u.y); acc[3] += w * bfhi(u.y);
    acc[4] += w * bflo(u.z); acc[5] += w * bfhi(u.z);
    acc[6] += w * bflo(u.w); acc[7] += w * bfhi(u.w);
  };

  for (int base = 0; base < deg; base += 64) {
    int i = base + lane;
    if (i < deg) {
      int s = csr_src[off + i];
      float l0 = a_src[s * 2 + 0] + ad0;
      float l1 = a_src[s * 2 + 1] + ad1;
      l0 = l0 > 0.f ? l0 : 0.2f * l0;
      l1 = l1 > 0.f ? l1 : 0.2f * l1;
      meta[wv][lane] = make_int4(s, __float_as_int(__expf(l0)), __float_as_int(__expf(l1)), 0);
    }
    int cnt = min(64, deg - base);
    int j = 0;
    for (; j + 8 <= cnt; j += 8) {
      proc(j + half); proc(j + 2 + half); proc(j + 4 + half); proc(j + 6 + half);
    }
    for (; j + 2 <= cnt; j += 2) proc(j + half);
    if (j < cnt && half == 0) proc(j);
  }
  // combine the two half-wave partial sums
#pragma unroll
  for (int k = 0; k < 8; ++k) acc[k] += __shfl_xor(acc[k], 32);
  den += __shfl_xor(den, 32);

  float inv = 1.f / (den + 1e-16f);
  float4 b01 = *(const float4*)(b1 + l5 * 8);
  float4 b23 = *(const float4*)(b1 + l5 * 8 + 4);
  float bb[8] = {b01.x, b01.y, b01.z, b01.w, b23.x, b23.y, b23.z, b23.w};
  u16 tmp[8];
#pragma unroll
  for (int k = 0; k < 8; ++k) {
    float o = acc[k] * inv + bb[k];
    o = o > 0.f ? o : expm1f(o);
    tmp[k] = f2bf(o);
  }
  if (half == 0) *(uint4*)(out + (size_t)node * 256 + l5 * 8) = *(uint4*)tmp;
}

// ---------------- layer-2 aggregation: 8 edges/wave-step + log_softmax ----------------
__global__ void agg2_kernel(const u16* __restrict__ H2, const int* __restrict__ offsets,
                            const int* __restrict__ csr_src,
                            const float* __restrict__ a_src, const float* __restrict__ a_dst,
                            const float* __restrict__ b2, float* __restrict__ out, int N) {
  __shared__ int2 meta[4][64];
  int wv = threadIdx.x >> 6;
  int lane = threadIdx.x & 63;
  int node = blockIdx.x * 4 + wv;
  if (node >= N) return;
  int off = offsets[node];
  int deg = offsets[node + 1] - off;
  float ad = a_dst[node];
  const int grp = lane >> 3;      // which edge of an 8-group
  const int l3 = lane & 7;        // owns channels l3*8 .. l3*8+7
  const char* H2c = (const char*)H2;
  const unsigned loff = (unsigned)(l3 * 16);
  float acc[8] = {0.f, 0.f, 0.f, 0.f, 0.f, 0.f, 0.f, 0.f};
  float den = 0.f;
  const int2* mw = meta[wv];

  auto proc = [&](int jj) {
    int2 m = mw[jj];
    float w = __int_as_float(m.y);
    uint4 u = *(const uint4*)(H2c + (((unsigned)m.x << 7) + loff));
    den += w;
    acc[0] += w * bflo(u.x); acc[1] += w * bfhi(u.x);
    acc[2] += w * bflo(u.y); acc[3] += w * bfhi(u.y);
    acc[4] += w * bflo(u.z); acc[5] += w * bfhi(u.z);
    acc[6] += w * bflo(u.w); acc[7] += w * bfhi(u.w);
  };

  for (int base = 0; base < deg; base += 64) {
    int i = base + lane;
    if (i < deg) {
      int s = csr_src[off + i];
      float l = a_src[s] + ad;
      l = l > 0.f ? l : 0.2f * l;
      meta[wv][lane] = make_int2(s, __float_as_int(__expf(l)));
    }
    int cnt = min(64, deg - base);
    int j = 0;
    for (; j + 16 <= cnt; j += 16) { proc(j + grp); proc(j + 8 + grp); }
    for (; j + 8 <= cnt; j += 8) proc(j + grp);
    int r = cnt - j;
    if (r > 0 && grp < r) proc(j + grp);
  }
  // combine across the 8 groups (lane bits 3,4,5)
#pragma unroll
  for (int k = 0; k < 8; ++k) {
    acc[k] += __shfl_xor(acc[k], 8);
    acc[k] += __shfl_xor(acc[k], 16);
    acc[k] += __shfl_xor(acc[k], 32);
  }
  den += __shfl_xor(den, 8);
  den += __shfl_xor(den, 16);
  den += __shfl_xor(den, 32);

  float inv = 1.f / (den + 1e-16f);
  float4 b01 = *(const float4*)(b2 + l3 * 8);
  float4 b23 = *(const float4*)(b2 + l3 * 8 + 4);
  float bb[8] = {b01.x, b01.y, b01.z, b01.w, b23.x, b23.y, b23.z, b23.w};
  float v[8];
#pragma unroll
  for (int k = 0; k < 8; ++k) v[k] = acc[k] * inv + bb[k];
  // log_softmax over 64 classes: each lane holds 8, 8 lanes per group cover all
  float m = v[0];
#pragma unroll
  for (int k = 1; k < 8; ++k) m = fmaxf(m, v[k]);
  m = fmaxf(m, __shfl_xor(m, 1));
  m = fmaxf(m, __shfl_xor(m, 2));
  m = fmaxf(m, __shfl_xor(m, 4));
  float sum = 0.f;
#pragma unroll
  for (int k = 0; k < 8; ++k) sum += __expf(v[k] - m);
  sum += __shfl_xor(sum, 1);
  sum += __shfl_xor(sum, 2);
  sum += __shfl_xor(sum, 4);
  float ls = m + logf(sum);
  if (lane < 8) {
    float4 o0 = make_float4(v[0] - ls, v[1] - ls, v[2] - ls, v[3] - ls);
    float4 o1 = make_float4(v[4] - ls, v[5] - ls, v[6] - ls, v[7] - ls);
    *(float4*)(out + (size_t)node * 64 + l3 * 8) = o0;
    *(float4*)(out + (size_t)node * 64 + l3 * 8 + 4) = o1;
  }
}

// ---------------- launch ----------------
extern "C" void kernel_launch(void* const* d_in, const int* in_sizes, int n_in,
                              void* d_out, int out_size, void* d_ws, size_t ws_size,
                              hipStream_t stream) {
  const float* x   = (const float*)d_in[0];
  const int*   ei  = (const int*)d_in[1];
  const float* W1  = (const float*)d_in[2];
  const float* as1 = (const float*)d_in[3];
  const float* ad1 = (const float*)d_in[4];
  const float* b1  = (const float*)d_in[5];
  const float* W2  = (const float*)d_in[6];
  const float* as2 = (const float*)d_in[7];
  const float* ad2 = (const float*)d_in[8];
  const float* b2  = (const float*)d_in[9];
  float* out = (float*)d_out;

  const int N  = in_sizes[0] / 256;
  const int E  = in_sizes[1] / 2;
  const int Et = E + N;
  const int nb = (N + 255) / 256;
  const int nbc = (Et + 255) / 256;
  const int nbt = (256 * 256 + 64 * 256 + 255) / 256;

  char* p = (char*)d_ws;
  auto alloc = [&](size_t bytes) -> char* {
    char* r = p;
    p += (bytes + 255) & ~(size_t)255;
    return r;
  };
  u16* H1b     = (u16*)alloc((size_t)N * 256 * 2);
  u16* h1act   = (u16*)alloc((size_t)N * 256 * 2);
  u16* H2b     = (u16*)alloc((size_t)N * 64 * 2);
  u16* W1T     = (u16*)alloc((size_t)256 * 256 * 2);
  u16* W2T     = (u16*)alloc((size_t)64 * 256 * 2);
  float* a_src1 = (float*)alloc((size_t)N * 2 * 4);
  float* a_dst1 = (float*)alloc((size_t)N * 2 * 4);
  float* a_src2 = (float*)alloc((size_t)N * 4);
  float* a_dst2 = (float*)alloc((size_t)N * 4);
  int* counts   = (int*)alloc((size_t)N * 4);
  int* offsets  = (int*)alloc((size_t)(N + 1) * 4);
  int* cursor   = (int*)alloc((size_t)N * 4);
  int* bsums    = (int*)alloc((size_t)1024 * 4);
  int* csr_src  = (int*)alloc((size_t)Et * 4);

  const int tb = 256;

  // CSR build + weight prep
  hipMemsetAsync(counts, 0, (size_t)N * 4, stream);
  prep_kernel<<<nbc + nbt, tb, 0, stream>>>(ei, E, N, counts, W1, W2, W1T, W2T, nbc);
  block_scan_kernel<<<nb, 256, 0, stream>>>(counts, offsets, bsums, N);
  scan_sums_kernel<<<1, 1024, 0, stream>>>(bsums, offsets, nb, N);
  add_base_kernel<<<nb, 256, 0, stream>>>(offsets, cursor, bsums, N);
  scatter_kernel<<<(Et + tb - 1) / tb, tb, 0, stream>>>(ei, E, N, cursor, csr_src);

  // layer 1: gemm + fused a1
  mfma_gemm<64, 256, 32, 64, 64, true, 1><<<(N + 63) / 64, 256, 0, stream>>>(
      x, W1T, H1b, as1, ad1, a_src1, a_dst1, N, 256);
  agg1_kernel<<<(N + 3) / 4, 256, 0, stream>>>(H1b, offsets, csr_src, a_src1, a_dst1, b1,
                                               h1act, N);

  // layer 2: gemm + fused a2
  mfma_gemm<128, 64, 32, 32, 64, false, 2><<<(N + 127) / 128, 256, 0, stream>>>(
      h1act, W2T, H2b, as2, ad2, a_src2, a_dst2, N, 256);
  agg2_kernel<<<(N + 3) / 4, 256, 0, stream>>>(H2b, offsets, csr_src, a_src2, a_dst2, b2,
                                               out, N);
}